// Round 1
// baseline (6827.307 us; speedup 1.0000x reference)
//
#include <hip/hip_runtime.h>
#include <hip/hip_bf16.h>

// Problem constants (B=1)
#define S_LEN 2048
#define HID 2048
#define NH 16
#define HD 256
#define NROT 64
#define NOPE 192
#define QL 1024
#define OR_ 512
#define NG 4
#define HPG 4
#define EPS 1e-6f
#define SCALE 0.0625f   // 256^-0.5

// ---------------- Generic fp32 GEMM: C[M,N] = A[M,K] @ B[N,K]^T ----------------
// A row-major lda, B row-major ldb (B is the weight, N x K), C row-major ldc.
// All M,N multiples of 64; K multiple of 16 (true for every call here).
#define TILE 64
#define BK 16
__global__ __launch_bounds__(256) void gemm_abt(
    const float* __restrict__ A, const float* __restrict__ B, float* __restrict__ C,
    int M, int N, int K, int lda, int ldb, int ldc) {
  __shared__ float As[BK][TILE];
  __shared__ float Bs[BK][TILE];
  int tid = threadIdx.x;
  int m0 = blockIdx.y * TILE;
  int n0 = blockIdx.x * TILE;
  int tx = tid & 15, ty = tid >> 4;
  int lk = tid & 15;       // k within chunk
  int lm = tid >> 4;       // row within 16-group
  float acc[4][4] = {};
  for (int k0 = 0; k0 < K; k0 += BK) {
#pragma unroll
    for (int r = 0; r < 4; ++r) {
      As[lk][lm + 16 * r] = A[(size_t)(m0 + lm + 16 * r) * lda + k0 + lk];
      Bs[lk][lm + 16 * r] = B[(size_t)(n0 + lm + 16 * r) * ldb + k0 + lk];
    }
    __syncthreads();
#pragma unroll
    for (int kk = 0; kk < BK; ++kk) {
      float a[4], b[4];
#pragma unroll
      for (int i = 0; i < 4; ++i) a[i] = As[kk][ty * 4 + i];
#pragma unroll
      for (int j = 0; j < 4; ++j) b[j] = Bs[kk][tx * 4 + j];
#pragma unroll
      for (int i = 0; i < 4; ++i)
#pragma unroll
        for (int j = 0; j < 4; ++j) acc[i][j] += a[i] * b[j];
    }
    __syncthreads();
  }
#pragma unroll
  for (int i = 0; i < 4; ++i)
#pragma unroll
    for (int j = 0; j < 4; ++j)
      C[(size_t)(m0 + ty * 4 + i) * ldc + n0 + tx * 4 + j] = acc[i][j];
}

// ---------------- RMSNorm over rows of length L (with weight), in place ----------------
__global__ __launch_bounds__(256) void rmsnorm_rows(float* __restrict__ x,
                                                    const float* __restrict__ w, int L) {
  int row = blockIdx.x;
  float* p = x + (size_t)row * L;
  __shared__ float red[256];
  float s = 0.f;
  for (int i = threadIdx.x; i < L; i += 256) { float v = p[i]; s += v * v; }
  red[threadIdx.x] = s;
  __syncthreads();
  for (int off = 128; off > 0; off >>= 1) {
    if (threadIdx.x < off) red[threadIdx.x] += red[threadIdx.x + off];
    __syncthreads();
  }
  float r = rsqrtf(red[0] / (float)L + EPS);
  for (int i = threadIdx.x; i < L; i += 256) p[i] = p[i] * r * w[i];
}

// ---------------- Q per-head RMS (no weight) + RoPE on last 64 dims, in place ----------------
// One block per (s, h) row of 256.
__global__ __launch_bounds__(256) void qnorm_rope(float* __restrict__ q,
                                                  const float* __restrict__ freqs) {
  int row = blockIdx.x;       // s*NH + h
  int s = row / NH;
  float* p = q + (size_t)row * HD;
  int d = threadIdx.x;
  float v = p[d];
  __shared__ float red[256];
  __shared__ float sm[256];
  red[d] = v * v;
  __syncthreads();
  for (int off = 128; off > 0; off >>= 1) {
    if (d < off) red[d] += red[d + off];
    __syncthreads();
  }
  float r = rsqrtf(red[0] / 256.0f + EPS);
  float nv = v * r;
  sm[d] = nv;
  __syncthreads();
  float outv = nv;
  if (d >= NOPE) {
    int j = (d - NOPE) >> 1;
    float f = freqs[(size_t)s * (NROT / 2) + j];
    float c = cosf(f), si = sinf(f);
    float x1 = sm[NOPE + 2 * j], x2 = sm[NOPE + 2 * j + 1];
    outv = ((d & 1) == 0) ? (x1 * c - x2 * si) : (x1 * si + x2 * c);
  }
  p[d] = outv;
}

// ---------------- KV RMS (with weight) + RoPE on last 64 dims, in place ----------------
__global__ __launch_bounds__(256) void kvnorm_rope(float* __restrict__ kv,
                                                   const float* __restrict__ w,
                                                   const float* __restrict__ freqs) {
  int s = blockIdx.x;
  float* p = kv + (size_t)s * HD;
  int d = threadIdx.x;
  float v = p[d];
  __shared__ float red[256];
  __shared__ float sm[256];
  red[d] = v * v;
  __syncthreads();
  for (int off = 128; off > 0; off >>= 1) {
    if (d < off) red[d] += red[d + off];
    __syncthreads();
  }
  float r = rsqrtf(red[0] / 256.0f + EPS);
  float nv = v * r * w[d];
  sm[d] = nv;
  __syncthreads();
  float outv = nv;
  if (d >= NOPE) {
    int j = (d - NOPE) >> 1;
    float f = freqs[(size_t)s * (NROT / 2) + j];
    float c = cosf(f), si = sinf(f);
    float x1 = sm[NOPE + 2 * j], x2 = sm[NOPE + 2 * j + 1];
    outv = ((d & 1) == 0) ? (x1 * c - x2 * si) : (x1 * si + x2 * c);
  }
  p[d] = outv;
}

// ---------------- Causal flash attention with sink, + conj-RoPE epilogue ----------------
// Block per (s, h), 256 threads. Online softmax over key chunks of 256.
// Writes o laid out (s, h*256+d) == the grouped layout needed downstream.
__global__ __launch_bounds__(256) void attention(
    const float* __restrict__ q, const float* __restrict__ kv,
    const float* __restrict__ sink, const float* __restrict__ freqs,
    float* __restrict__ o) {
  int s = blockIdx.x;
  int h = blockIdx.y;
  int tid = threadIdx.x;
  __shared__ float qs[256];
  __shared__ float ps[256];
  __shared__ float red[256];
  __shared__ float m_s, l_s, alpha_s;
  qs[tid] = q[((size_t)s * NH + h) * HD + tid];
  if (tid == 0) { m_s = -1e30f; l_s = 0.f; }
  __syncthreads();
  float o_acc = 0.f;
  int nch = s / 256 + 1;
  for (int ch = 0; ch < nch; ++ch) {
    int t = ch * 256 + tid;
    float sc = -1e30f;
    if (t <= s) {
      const float* kr = kv + (size_t)t * HD;
      float acc = 0.f;
#pragma unroll 8
      for (int dd = 0; dd < HD; ++dd) acc += qs[dd] * kr[dd];
      sc = acc * SCALE;
    }
    red[tid] = sc;
    __syncthreads();
    for (int off = 128; off > 0; off >>= 1) {
      if (tid < off) red[tid] = fmaxf(red[tid], red[tid + off]);
      __syncthreads();
    }
    if (tid == 0) {
      float mold = m_s;
      float mnew = fmaxf(mold, red[0]);
      m_s = mnew;
      alpha_s = expf(mold - mnew);
    }
    __syncthreads();
    float mnew = m_s;
    float alpha = alpha_s;
    float p = (t <= s) ? expf(sc - mnew) : 0.f;
    ps[tid] = p;
    red[tid] = p;
    __syncthreads();
    for (int off = 128; off > 0; off >>= 1) {
      if (tid < off) red[tid] += red[tid + off];
      __syncthreads();
    }
    if (tid == 0) l_s = l_s * alpha + red[0];
    // accumulate o: thread tid owns dim d = tid
    o_acc *= alpha;
    int base = ch * 256;
#pragma unroll 4
    for (int i = 0; i < 256; ++i)
      o_acc += ps[i] * kv[(size_t)(base + i) * HD + tid];
    __syncthreads();
  }
  float m = m_s;
  float l = l_s + expf(sink[h] - m);
  float ov = o_acc / l;
  // conj RoPE on last 64 dims
  __shared__ float osm[256];
  osm[tid] = ov;
  __syncthreads();
  float outv = ov;
  if (tid >= NOPE) {
    int j = (tid - NOPE) >> 1;
    float f = freqs[(size_t)s * (NROT / 2) + j];
    float c = cosf(f), si = sinf(f);
    float x1 = osm[NOPE + 2 * j], x2 = osm[NOPE + 2 * j + 1];
    // conj: sin -> -sin
    outv = ((tid & 1) == 0) ? (x1 * c + x2 * si) : (-x1 * si + x2 * c);
  }
  o[((size_t)s * NH + h) * HD + tid] = outv;
}

extern "C" void kernel_launch(void* const* d_in, const int* in_sizes, int n_in,
                              void* d_out, int out_size, void* d_ws, size_t ws_size,
                              hipStream_t stream) {
  const float* x        = (const float*)d_in[0];  // (S, HID)
  const float* freqs    = (const float*)d_in[1];  // (S, 32)
  const float* wq_a     = (const float*)d_in[2];  // (QL, HID)
  const float* q_norm_w = (const float*)d_in[3];  // (QL,)
  const float* wq_b     = (const float*)d_in[4];  // (H*D, QL)
  const float* wkv      = (const float*)d_in[5];  // (D, HID)
  const float* kv_norm_w= (const float*)d_in[6];  // (D,)
  const float* wo_a_w   = (const float*)d_in[7];  // (G*OR, HPG*D)
  const float* wo_b     = (const float*)d_in[8];  // (HID, G*OR)
  const float* sink     = (const float*)d_in[9];  // (H,)
  float* out = (float*)d_out;

  // Workspace layout (floats). Lifetimes: qa: g1->g2; kv: g3->attn; q: g2->attn;
  // o: attn->g4; o_r: g4->g5 (aliases qa/kv/q-head which are dead by then).
  float* ws = (float*)d_ws;
  size_t off_qa = 0;                                   // 2048*1024
  size_t off_kv = (size_t)S_LEN * QL;                  // 2048*256
  size_t off_q  = off_kv + (size_t)S_LEN * HD;         // 2048*4096
  size_t off_o  = off_q + (size_t)S_LEN * NH * HD;     // 2048*4096
  size_t off_or = 0;                                   // 2048*2048, aliased
  float* qa  = ws + off_qa;
  float* kvb = ws + off_kv;
  float* qbuf= ws + off_q;
  float* obuf= ws + off_o;
  float* orb = ws + off_or;

  dim3 blk(256);

  // 1) qa = x @ wq_a^T   (2048x1024, K=2048)
  gemm_abt<<<dim3(QL / TILE, S_LEN / TILE), blk, 0, stream>>>(
      x, wq_a, qa, S_LEN, QL, HID, HID, HID, QL);
  // 2) RMS(qa) * q_norm_w
  rmsnorm_rows<<<dim3(S_LEN), blk, 0, stream>>>(qa, q_norm_w, QL);
  // 3) q = qa @ wq_b^T   (2048x4096, K=1024)
  gemm_abt<<<dim3(NH * HD / TILE, S_LEN / TILE), blk, 0, stream>>>(
      qa, wq_b, qbuf, S_LEN, NH * HD, QL, QL, QL, NH * HD);
  // 4) per-(s,h) RMS + RoPE
  qnorm_rope<<<dim3(S_LEN * NH), blk, 0, stream>>>(qbuf, freqs);
  // 5) kv = x @ wkv^T    (2048x256, K=2048)
  gemm_abt<<<dim3(HD / TILE, S_LEN / TILE), blk, 0, stream>>>(
      x, wkv, kvb, S_LEN, HD, HID, HID, HID, HD);
  // 6) RMS(kv)*w + RoPE
  kvnorm_rope<<<dim3(S_LEN), blk, 0, stream>>>(kvb, kv_norm_w, freqs);
  // 7) attention -> obuf (s, h*256+d)
  attention<<<dim3(S_LEN, NH), blk, 0, stream>>>(qbuf, kvb, sink, freqs, obuf);
  // 8) grouped projection: per g, o_r[:, g*OR:(g+1)*OR] = o_g @ wo_a_w[g]^T
  for (int g = 0; g < NG; ++g) {
    gemm_abt<<<dim3(OR_ / TILE, S_LEN / TILE), blk, 0, stream>>>(
        obuf + (size_t)g * HPG * HD, wo_a_w + (size_t)g * OR_ * (HPG * HD),
        orb + (size_t)g * OR_,
        S_LEN, OR_, HPG * HD, NH * HD, HPG * HD, NG * OR_);
  }
  // 9) out = o_r @ wo_b^T (2048x2048, K=2048)
  gemm_abt<<<dim3(HID / TILE, S_LEN / TILE), blk, 0, stream>>>(
      orb, wo_b, out, S_LEN, HID, NG * OR_, NG * OR_, NG * OR_, HID);
}

// Round 3
// 2183.091 us; speedup vs baseline: 3.1274x; 3.1274x over previous
//
#include <hip/hip_runtime.h>
#include <hip/hip_bf16.h>

// Problem constants (B=1)
#define S_LEN 2048
#define HID 2048
#define NH 16
#define HD 256
#define NROT 64
#define NOPE 192
#define QL 1024
#define OR_ 512
#define NG 4
#define HPG 4
#define EPS 1e-6f
#define SCALE 0.0625f   // 256^-0.5

typedef __bf16 bf16x8 __attribute__((ext_vector_type(8)));
typedef short s16x8 __attribute__((ext_vector_type(8)));
typedef float f32x4 __attribute__((ext_vector_type(4)));

__device__ __forceinline__ unsigned short f2bf(float x) {
  unsigned int u = __builtin_bit_cast(unsigned int, x);
  u += 0x7FFFu + ((u >> 16) & 1u);   // RNE (values here are finite, non-NaN)
  return (unsigned short)(u >> 16);
}

// ---------------- Generic fp32 GEMM: C[M,N] = A[M,K] @ B[N,K]^T ----------------
#define TILE 64
#define BK 16
__global__ __launch_bounds__(256) void gemm_abt(
    const float* __restrict__ A, const float* __restrict__ B, float* __restrict__ C,
    int M, int N, int K, int lda, int ldb, int ldc) {
  __shared__ float As[BK][TILE];
  __shared__ float Bs[BK][TILE];
  int tid = threadIdx.x;
  int m0 = blockIdx.y * TILE;
  int n0 = blockIdx.x * TILE;
  int tx = tid & 15, ty = tid >> 4;
  int lk = tid & 15;
  int lm = tid >> 4;
  float acc[4][4] = {};
  for (int k0 = 0; k0 < K; k0 += BK) {
#pragma unroll
    for (int r = 0; r < 4; ++r) {
      As[lk][lm + 16 * r] = A[(size_t)(m0 + lm + 16 * r) * lda + k0 + lk];
      Bs[lk][lm + 16 * r] = B[(size_t)(n0 + lm + 16 * r) * ldb + k0 + lk];
    }
    __syncthreads();
#pragma unroll
    for (int kk = 0; kk < BK; ++kk) {
      float a[4], b[4];
#pragma unroll
      for (int i = 0; i < 4; ++i) a[i] = As[kk][ty * 4 + i];
#pragma unroll
      for (int j = 0; j < 4; ++j) b[j] = Bs[kk][tx * 4 + j];
#pragma unroll
      for (int i = 0; i < 4; ++i)
#pragma unroll
        for (int j = 0; j < 4; ++j) acc[i][j] += a[i] * b[j];
    }
    __syncthreads();
  }
#pragma unroll
  for (int i = 0; i < 4; ++i)
#pragma unroll
    for (int j = 0; j < 4; ++j)
      C[(size_t)(m0 + ty * 4 + i) * ldc + n0 + tx * 4 + j] = acc[i][j];
}

// ---------------- RMSNorm over rows of length L (with weight), in place ----------------
__global__ __launch_bounds__(256) void rmsnorm_rows(float* __restrict__ x,
                                                    const float* __restrict__ w, int L) {
  int row = blockIdx.x;
  float* p = x + (size_t)row * L;
  __shared__ float red[256];
  float s = 0.f;
  for (int i = threadIdx.x; i < L; i += 256) { float v = p[i]; s += v * v; }
  red[threadIdx.x] = s;
  __syncthreads();
  for (int off = 128; off > 0; off >>= 1) {
    if (threadIdx.x < off) red[threadIdx.x] += red[threadIdx.x + off];
    __syncthreads();
  }
  float r = rsqrtf(red[0] / (float)L + EPS);
  for (int i = threadIdx.x; i < L; i += 256) p[i] = p[i] * r * w[i];
}

// ---------------- Q per-head RMS (no weight) + RoPE, fp32 in -> bf16 out ----------------
__global__ __launch_bounds__(256) void qnorm_rope_bf(const float* __restrict__ q,
                                                     const float* __restrict__ freqs,
                                                     unsigned short* __restrict__ qo) {
  int row = blockIdx.x;       // s*NH + h
  int s = row / NH;
  const float* p = q + (size_t)row * HD;
  int d = threadIdx.x;
  float v = p[d];
  __shared__ float red[256];
  __shared__ float sm[256];
  red[d] = v * v;
  __syncthreads();
  for (int off = 128; off > 0; off >>= 1) {
    if (d < off) red[d] += red[d + off];
    __syncthreads();
  }
  float r = rsqrtf(red[0] / 256.0f + EPS);
  float nv = v * r;
  sm[d] = nv;
  __syncthreads();
  float outv = nv;
  if (d >= NOPE) {
    int j = (d - NOPE) >> 1;
    float f = freqs[(size_t)s * (NROT / 2) + j];
    float c = cosf(f), si = sinf(f);
    float x1 = sm[NOPE + 2 * j], x2 = sm[NOPE + 2 * j + 1];
    outv = ((d & 1) == 0) ? (x1 * c - x2 * si) : (x1 * si + x2 * c);
  }
  qo[(size_t)row * HD + d] = f2bf(outv);
}

// ---------------- KV RMS (with weight) + RoPE, fp32 in -> bf16 out ----------------
__global__ __launch_bounds__(256) void kvnorm_rope_bf(const float* __restrict__ kv,
                                                      const float* __restrict__ w,
                                                      const float* __restrict__ freqs,
                                                      unsigned short* __restrict__ ko) {
  int s = blockIdx.x;
  const float* p = kv + (size_t)s * HD;
  int d = threadIdx.x;
  float v = p[d];
  __shared__ float red[256];
  __shared__ float sm[256];
  red[d] = v * v;
  __syncthreads();
  for (int off = 128; off > 0; off >>= 1) {
    if (d < off) red[d] += red[d + off];
    __syncthreads();
  }
  float r = rsqrtf(red[0] / 256.0f + EPS);
  float nv = v * r * w[d];
  sm[d] = nv;
  __syncthreads();
  float outv = nv;
  if (d >= NOPE) {
    int j = (d - NOPE) >> 1;
    float f = freqs[(size_t)s * (NROT / 2) + j];
    float c = cosf(f), si = sinf(f);
    float x1 = sm[NOPE + 2 * j], x2 = sm[NOPE + 2 * j + 1];
    outv = ((d & 1) == 0) ? (x1 * c - x2 * si) : (x1 * si + x2 * c);
  }
  ko[(size_t)s * HD + d] = f2bf(outv);
}

// ---------------- MFMA flash attention: 64 q-rows x 1 head per block ----------------
// 4 waves, each owns 16 q-rows. kv chunks of 32 staged to LDS (row-major for
// QK^T B-frags, transposed for PV B-frags — K and V are the same tensor).
// Online softmax in MFMA C-layout; P via padded LDS round-trip; sink +
// conj-RoPE fused epilogue. Output fp32 (s, h*256+d).
__global__ __launch_bounds__(256) void attn_mfma(
    const unsigned short* __restrict__ qbf,   // (S, NH*HD) bf16 bits
    const unsigned short* __restrict__ kvbf,  // (S, HD) bf16 bits
    const float* __restrict__ sink,
    const float* __restrict__ freqs,
    float* __restrict__ o) {
  __shared__ __align__(16) unsigned short kv_s[32 * 264];    // [t][d], stride 264
  __shared__ __align__(16) unsigned short kvT_s[256 * 40];   // [d][t], stride 40
  __shared__ __align__(16) unsigned short p_s[64 * 40];      // [s_local][t], stride 40

  const int tid = threadIdx.x;
  const int wave = tid >> 6, lane = tid & 63;
  const int col = lane & 15, grp = lane >> 4;
  const int q0 = (gridDim.x - 1 - blockIdx.x) * 64;   // big tiles first (LPT)
  const int h = blockIdx.y;
  const int qrow_base = q0 + wave * 16;

  // Q fragments in registers: qf[ko] covers dims [ko*32 + grp*8, +8)
  s16x8 qf[8];
  {
    const size_t base = (size_t)(qrow_base + col) * (NH * HD) + (size_t)h * HD + grp * 8;
#pragma unroll
    for (int ko = 0; ko < 8; ++ko)
      qf[ko] = *(const s16x8*)(qbf + base + ko * 32);
  }

  float m_i[4], l_i[4];
#pragma unroll
  for (int r = 0; r < 4; ++r) { m_i[r] = -1e30f; l_i[r] = 0.f; }
  f32x4 oacc[16];
#pragma unroll
  for (int nt = 0; nt < 16; ++nt) oacc[nt] = (f32x4){0.f, 0.f, 0.f, 0.f};

  const int nch = q0 / 32 + 2;
  for (int ch = 0; ch < nch; ++ch) {
    const int t0 = ch * 32;
    // ---- stage kv chunk: row-major + transposed ----
#pragma unroll
    for (int rep = 0; rep < 4; ++rep) {
      int u = rep * 256 + tid;
      int t = u >> 5;              // 32 x 16B units per row
      int d = (u & 31) * 8;
      s16x8 v = *(const s16x8*)(kvbf + (size_t)(t0 + t) * HD + d);
      *(s16x8*)&kv_s[t * 264 + d] = v;
    }
    {
      int t = tid & 31, d0 = (tid >> 5) * 32;
      const unsigned short* src = kvbf + (size_t)(t0 + t) * HD + d0;
#pragma unroll
      for (int u = 0; u < 4; ++u) {
        s16x8 v = *(const s16x8*)(src + u * 8);
#pragma unroll
        for (int j = 0; j < 8; ++j)
          kvT_s[(d0 + u * 8 + j) * 40 + t] = (unsigned short)v[j];
      }
    }
    __syncthreads();

    // ---- QK^T: two 16x16 key tiles ----
    f32x4 sc[2];
    sc[0] = (f32x4){0.f, 0.f, 0.f, 0.f};
    sc[1] = (f32x4){0.f, 0.f, 0.f, 0.f};
#pragma unroll
    for (int ko = 0; ko < 8; ++ko) {
#pragma unroll
      for (int kt = 0; kt < 2; ++kt) {
        s16x8 bf = *(const s16x8*)&kv_s[(kt * 16 + col) * 264 + ko * 32 + grp * 8];
        sc[kt] = __builtin_amdgcn_mfma_f32_16x16x32_bf16(
            __builtin_bit_cast(bf16x8, qf[ko]), __builtin_bit_cast(bf16x8, bf),
            sc[kt], 0, 0, 0);
      }
    }
    // ---- scale + causal mask ----
#pragma unroll
    for (int kt = 0; kt < 2; ++kt)
#pragma unroll
      for (int r = 0; r < 4; ++r) {
        int tg = t0 + kt * 16 + col;
        int sg = qrow_base + grp * 4 + r;
        float v = sc[kt][r] * SCALE;
        sc[kt][r] = (tg <= sg) ? v : -1e30f;
      }
    // ---- online softmax: row max, alpha, p, row sum ----
    float alpha[4];
#pragma unroll
    for (int r = 0; r < 4; ++r) {
      float v = fmaxf(sc[0][r], sc[1][r]);
      v = fmaxf(v, __shfl_xor(v, 1));
      v = fmaxf(v, __shfl_xor(v, 2));
      v = fmaxf(v, __shfl_xor(v, 4));
      v = fmaxf(v, __shfl_xor(v, 8));
      float mn = fmaxf(m_i[r], v);
      alpha[r] = __expf(m_i[r] - mn);
      m_i[r] = mn;
    }
    float rs[4] = {0.f, 0.f, 0.f, 0.f};
#pragma unroll
    for (int kt = 0; kt < 2; ++kt)
#pragma unroll
      for (int r = 0; r < 4; ++r) {
        float p = __expf(sc[kt][r] - m_i[r]);
        rs[r] += p;
        p_s[(wave * 16 + grp * 4 + r) * 40 + kt * 16 + col] = f2bf(p);
      }
#pragma unroll
    for (int r = 0; r < 4; ++r) {
      float v = rs[r];
      v += __shfl_xor(v, 1);
      v += __shfl_xor(v, 2);
      v += __shfl_xor(v, 4);
      v += __shfl_xor(v, 8);
      l_i[r] = l_i[r] * alpha[r] + v;
#pragma unroll
      for (int nt = 0; nt < 16; ++nt) oacc[nt][r] *= alpha[r];
    }
    __syncthreads();

    // ---- PV: P(16x32) @ KV(32x256) ----
    s16x8 pf = *(const s16x8*)&p_s[(wave * 16 + col) * 40 + grp * 8];
#pragma unroll
    for (int nt = 0; nt < 16; ++nt) {
      s16x8 vf = *(const s16x8*)&kvT_s[(nt * 16 + col) * 40 + grp * 8];
      oacc[nt] = __builtin_amdgcn_mfma_f32_16x16x32_bf16(
          __builtin_bit_cast(bf16x8, pf), __builtin_bit_cast(bf16x8, vf),
          oacc[nt], 0, 0, 0);
    }
    __syncthreads();
  }

  // ---- epilogue: sink, normalize, conj-RoPE on dims [192,256), store ----
  const float sk = sink[h];
  float inv[4];
#pragma unroll
  for (int r = 0; r < 4; ++r) inv[r] = 1.f / (l_i[r] + __expf(sk - m_i[r]));
#pragma unroll
  for (int nt = 0; nt < 16; ++nt) {
#pragma unroll
    for (int r = 0; r < 4; ++r) {
      float v = oacc[nt][r] * inv[r];
      int srow = qrow_base + grp * 4 + r;
      if (nt >= 12) {
        int dim = nt * 16 + col;
        int j = (dim - NOPE) >> 1;
        float f = freqs[(size_t)srow * (NROT / 2) + j];
        float c = cosf(f), si = sinf(f);
        float prt = __shfl_xor(v, 1);
        v = (col & 1) ? (v * c - prt * si) : (v * c + prt * si);
      }
      o[(size_t)srow * (NH * HD) + (size_t)h * HD + nt * 16 + col] = v;
    }
  }
}

extern "C" void kernel_launch(void* const* d_in, const int* in_sizes, int n_in,
                              void* d_out, int out_size, void* d_ws, size_t ws_size,
                              hipStream_t stream) {
  const float* x         = (const float*)d_in[0];
  const float* freqs     = (const float*)d_in[1];
  const float* wq_a      = (const float*)d_in[2];
  const float* q_norm_w  = (const float*)d_in[3];
  const float* wq_b      = (const float*)d_in[4];
  const float* wkv       = (const float*)d_in[5];
  const float* kv_norm_w = (const float*)d_in[6];
  const float* wo_a_w    = (const float*)d_in[7];
  const float* wo_b      = (const float*)d_in[8];
  const float* sink      = (const float*)d_in[9];
  float* out = (float*)d_out;

  // Workspace layout (float units), lifetime-aliased, total 14.75M floats = 59 MB:
  //  [0,2M)        qa fp32 (g1->g3)                       [dead after g3]
  //  [2M,10M)      qbuf fp32 (g3->qnorm); obuf (attn->g8) [distinct lifetimes]
  //  [10M,14M)     q_bf bf16 (qnorm->attn); orb fp32 4M (g8->g9)  <- FIX: was
  //                aliased to qa (2M) which overlapped obuf by 2M floats.
  //  [14M,14.5M)   kvb fp32 (g5->kvnorm)
  //  [14.5M,14.75M) kv_bf bf16 (kvnorm->attn)
  float* ws = (float*)d_ws;
  float* qa   = ws;
  float* qbuf = ws + (size_t)2 * 1024 * 1024;
  unsigned short* q_bf = (unsigned short*)(ws + (size_t)10 * 1024 * 1024);
  float* kvb  = ws + (size_t)14 * 1024 * 1024;
  unsigned short* kv_bf = (unsigned short*)(ws + (size_t)14 * 1024 * 1024 + 512 * 1024);
  float* obuf = qbuf;                                // alias: qbuf dead after qnorm
  float* orb  = ws + (size_t)10 * 1024 * 1024;       // alias: q_bf dead after attn

  dim3 blk(256);

  // 1) qa = x @ wq_a^T   (2048x1024, K=2048)
  gemm_abt<<<dim3(QL / TILE, S_LEN / TILE), blk, 0, stream>>>(
      x, wq_a, qa, S_LEN, QL, HID, HID, HID, QL);
  // 2) RMS(qa) * q_norm_w
  rmsnorm_rows<<<dim3(S_LEN), blk, 0, stream>>>(qa, q_norm_w, QL);
  // 3) qbuf = qa @ wq_b^T  (2048x4096, K=1024)
  gemm_abt<<<dim3(NH * HD / TILE, S_LEN / TILE), blk, 0, stream>>>(
      qa, wq_b, qbuf, S_LEN, NH * HD, QL, QL, QL, NH * HD);
  // 4) per-(s,h) RMS + RoPE -> bf16
  qnorm_rope_bf<<<dim3(S_LEN * NH), blk, 0, stream>>>(qbuf, freqs, q_bf);
  // 5) kvb = x @ wkv^T   (2048x256, K=2048)
  gemm_abt<<<dim3(HD / TILE, S_LEN / TILE), blk, 0, stream>>>(
      x, wkv, kvb, S_LEN, HD, HID, HID, HID, HD);
  // 6) RMS(kvb)*w + RoPE -> bf16
  kvnorm_rope_bf<<<dim3(S_LEN), blk, 0, stream>>>(kvb, kv_norm_w, freqs, kv_bf);
  // 7) MFMA flash attention -> obuf fp32 (s, h*256+d)
  attn_mfma<<<dim3(S_LEN / 64, NH), blk, 0, stream>>>(q_bf, kv_bf, sink, freqs, obuf);
  // 8) grouped projection
  for (int g = 0; g < NG; ++g) {
    gemm_abt<<<dim3(OR_ / TILE, S_LEN / TILE), blk, 0, stream>>>(
        obuf + (size_t)g * HPG * HD, wo_a_w + (size_t)g * OR_ * (HPG * HD),
        orb + (size_t)g * OR_,
        S_LEN, OR_, HPG * HD, NH * HD, HPG * HD, NG * OR_);
  }
  // 9) out = orb @ wo_b^T (2048x2048, K=2048)
  gemm_abt<<<dim3(HID / TILE, S_LEN / TILE), blk, 0, stream>>>(
      orb, wo_b, out, S_LEN, HID, NG * OR_, NG * OR_, NG * OR_, HID);
}

// Round 5
// 925.173 us; speedup vs baseline: 7.3795x; 2.3597x over previous
//
#include <hip/hip_runtime.h>
#include <hip/hip_bf16.h>

// Problem constants (B=1)
#define S_LEN 2048
#define HID 2048
#define NH 16
#define HD 256
#define NROT 64
#define NOPE 192
#define QL 1024
#define OR_ 512
#define NG 4
#define HPG 4
#define EPS 1e-6f
#define SCALE 0.0625f   // 256^-0.5

typedef __bf16 bf16x8 __attribute__((ext_vector_type(8)));
typedef short s16x8 __attribute__((ext_vector_type(8)));
typedef float f32x4 __attribute__((ext_vector_type(4)));

__device__ __forceinline__ unsigned short f2bf(float x) {
  unsigned int u = __builtin_bit_cast(unsigned int, x);
  u += 0x7FFFu + ((u >> 16) & 1u);   // RNE
  return (unsigned short)(u >> 16);
}
__device__ __forceinline__ float bf2f(unsigned short b) {
  unsigned int u = ((unsigned int)b) << 16;
  return __builtin_bit_cast(float, u);
}

// ---------------- fp32 -> bf16 convert (vectorized) ----------------
__global__ __launch_bounds__(256) void f32_to_bf16(const float* __restrict__ in,
                                                   unsigned short* __restrict__ out, int n4) {
  int i = blockIdx.x * 256 + threadIdx.x;
  if (i < n4) {
    float4 v = ((const float4*)in)[i];
    ushort4 o;
    o.x = f2bf(v.x); o.y = f2bf(v.y); o.z = f2bf(v.z); o.w = f2bf(v.w);
    ((ushort4*)out)[i] = o;
  }
}

// ---------------- bf16 MFMA GEMM: C[M,N] = A[M,K] @ B[N,K]^T ----------------
// 128x128 tile, BK=32, 4 waves in 2x2, each wave 64x64 via 4x4 of 16x16x32 MFMA.
// A,B bf16 row-major; C fp32 or bf16 (store_bf). blockIdx.z strides by *offz.
__global__ __launch_bounds__(256, 2) void gemm_bf16(
    const unsigned short* __restrict__ A, const unsigned short* __restrict__ B,
    void* __restrict__ Cv, int K, int lda, int ldb, int ldc,
    long aoffz, long boffz, long coffz, int store_bf) {
  __shared__ __align__(16) unsigned short As[128 * 40];
  __shared__ __align__(16) unsigned short Bs[128 * 40];
  A += (size_t)blockIdx.z * aoffz;
  B += (size_t)blockIdx.z * boffz;
  const int tid = threadIdx.x;
  const int wave = tid >> 6, lane = tid & 63;
  const int col = lane & 15, grp = lane >> 4;
  const int wm = wave >> 1, wn = wave & 1;
  const int m0 = blockIdx.y * 128, n0 = blockIdx.x * 128;

  f32x4 acc[4][4];
#pragma unroll
  for (int i = 0; i < 4; ++i)
#pragma unroll
    for (int j = 0; j < 4; ++j) acc[i][j] = (f32x4){0.f, 0.f, 0.f, 0.f};

  for (int k0 = 0; k0 < K; k0 += 32) {
#pragma unroll
    for (int u = 0; u < 2; ++u) {
      int lin = u * 256 + tid;
      int r = lin >> 2, c8 = (lin & 3) * 8;
      *(s16x8*)&As[r * 40 + c8] = *(const s16x8*)(A + (size_t)(m0 + r) * lda + k0 + c8);
      *(s16x8*)&Bs[r * 40 + c8] = *(const s16x8*)(B + (size_t)(n0 + r) * ldb + k0 + c8);
    }
    __syncthreads();
    s16x8 a[4], b[4];
#pragma unroll
    for (int i = 0; i < 4; ++i)
      a[i] = *(const s16x8*)&As[(wm * 64 + i * 16 + col) * 40 + grp * 8];
#pragma unroll
    for (int j = 0; j < 4; ++j)
      b[j] = *(const s16x8*)&Bs[(wn * 64 + j * 16 + col) * 40 + grp * 8];
#pragma unroll
    for (int i = 0; i < 4; ++i)
#pragma unroll
      for (int j = 0; j < 4; ++j)
        acc[i][j] = __builtin_amdgcn_mfma_f32_16x16x32_bf16(
            __builtin_bit_cast(bf16x8, a[i]), __builtin_bit_cast(bf16x8, b[j]),
            acc[i][j], 0, 0, 0);
    __syncthreads();
  }

  if (store_bf) {
    unsigned short* C = (unsigned short*)Cv + (size_t)blockIdx.z * coffz;
#pragma unroll
    for (int i = 0; i < 4; ++i)
#pragma unroll
      for (int j = 0; j < 4; ++j)
#pragma unroll
        for (int r = 0; r < 4; ++r)
          C[(size_t)(m0 + wm * 64 + i * 16 + grp * 4 + r) * ldc +
            n0 + wn * 64 + j * 16 + col] = f2bf(acc[i][j][r]);
  } else {
    float* C = (float*)Cv + (size_t)blockIdx.z * coffz;
#pragma unroll
    for (int i = 0; i < 4; ++i)
#pragma unroll
      for (int j = 0; j < 4; ++j)
#pragma unroll
        for (int r = 0; r < 4; ++r)
          C[(size_t)(m0 + wm * 64 + i * 16 + grp * 4 + r) * ldc +
            n0 + wn * 64 + j * 16 + col] = acc[i][j][r];
  }
}

// ---------------- RMSNorm (weighted) in-place on bf16 rows of length L ----------------
__global__ __launch_bounds__(256) void rmsnorm_bf_ip(unsigned short* __restrict__ x,
                                                     const float* __restrict__ w, int L) {
  int row = blockIdx.x;
  unsigned short* p = x + (size_t)row * L;
  __shared__ float red[256];
  float s = 0.f;
  for (int i = threadIdx.x; i < L; i += 256) { float v = bf2f(p[i]); s += v * v; }
  red[threadIdx.x] = s;
  __syncthreads();
  for (int off = 128; off > 0; off >>= 1) {
    if (threadIdx.x < off) red[threadIdx.x] += red[threadIdx.x + off];
    __syncthreads();
  }
  float r = rsqrtf(red[0] / (float)L + EPS);
  for (int i = threadIdx.x; i < L; i += 256) p[i] = f2bf(bf2f(p[i]) * r * w[i]);
}

// ---------------- Q per-head RMS (no weight) + RoPE, in-place bf16 ----------------
__global__ __launch_bounds__(256) void qnorm_rope_ip(unsigned short* __restrict__ q,
                                                     const float* __restrict__ freqs) {
  int row = blockIdx.x;       // s*NH + h
  int s = row / NH;
  unsigned short* p = q + (size_t)row * HD;
  int d = threadIdx.x;
  float v = bf2f(p[d]);
  __shared__ float red[256];
  __shared__ float sm[256];
  red[d] = v * v;
  __syncthreads();
  for (int off = 128; off > 0; off >>= 1) {
    if (d < off) red[d] += red[d + off];
    __syncthreads();
  }
  float r = rsqrtf(red[0] / 256.0f + EPS);
  float nv = v * r;
  sm[d] = nv;
  __syncthreads();
  float outv = nv;
  if (d >= NOPE) {
    int j = (d - NOPE) >> 1;
    float f = freqs[(size_t)s * (NROT / 2) + j];
    float c = cosf(f), si = sinf(f);
    float x1 = sm[NOPE + 2 * j], x2 = sm[NOPE + 2 * j + 1];
    outv = ((d & 1) == 0) ? (x1 * c - x2 * si) : (x1 * si + x2 * c);
  }
  p[d] = f2bf(outv);
}

// ---------------- KV RMS (weighted) + RoPE, in-place bf16 ----------------
__global__ __launch_bounds__(256) void kvnorm_rope_ip(unsigned short* __restrict__ kv,
                                                      const float* __restrict__ w,
                                                      const float* __restrict__ freqs) {
  int s = blockIdx.x;
  unsigned short* p = kv + (size_t)s * HD;
  int d = threadIdx.x;
  float v = bf2f(p[d]);
  __shared__ float red[256];
  __shared__ float sm[256];
  red[d] = v * v;
  __syncthreads();
  for (int off = 128; off > 0; off >>= 1) {
    if (d < off) red[d] += red[d + off];
    __syncthreads();
  }
  float r = rsqrtf(red[0] / 256.0f + EPS);
  float nv = v * r * w[d];
  sm[d] = nv;
  __syncthreads();
  float outv = nv;
  if (d >= NOPE) {
    int j = (d - NOPE) >> 1;
    float f = freqs[(size_t)s * (NROT / 2) + j];
    float c = cosf(f), si = sinf(f);
    float x1 = sm[NOPE + 2 * j], x2 = sm[NOPE + 2 * j + 1];
    outv = ((d & 1) == 0) ? (x1 * c - x2 * si) : (x1 * si + x2 * c);
  }
  p[d] = f2bf(outv);
}

// ---------------- MFMA flash attention (bf16 out) ----------------
// __launch_bounds__(256,1): uncap VGPRs — R3's default cap caused ~950 MB of
// scratch-spill HBM writes per dispatch (oacc 64 + qf 32 VGPRs persistent).
__global__ __launch_bounds__(256, 1) void attn_mfma(
    const unsigned short* __restrict__ qbf,   // (S, NH*HD) bf16
    const unsigned short* __restrict__ kvbf,  // (S, HD) bf16
    const float* __restrict__ sink,
    const float* __restrict__ freqs,
    unsigned short* __restrict__ ob) {        // (S, NH*HD) bf16
  __shared__ __align__(16) unsigned short kv_s[32 * 264];
  __shared__ __align__(16) unsigned short kvT_s[256 * 40];
  __shared__ __align__(16) unsigned short p_s[64 * 40];

  const int tid = threadIdx.x;
  const int wave = tid >> 6, lane = tid & 63;
  const int col = lane & 15, grp = lane >> 4;
  const int q0 = (gridDim.x - 1 - blockIdx.x) * 64;   // big tiles first (LPT)
  const int h = blockIdx.y;
  const int qrow_base = q0 + wave * 16;

  s16x8 qf[8];
  {
    const size_t base = (size_t)(qrow_base + col) * (NH * HD) + (size_t)h * HD + grp * 8;
#pragma unroll
    for (int ko = 0; ko < 8; ++ko)
      qf[ko] = *(const s16x8*)(qbf + base + ko * 32);
  }

  float m_i[4], l_i[4];
#pragma unroll
  for (int r = 0; r < 4; ++r) { m_i[r] = -1e30f; l_i[r] = 0.f; }
  f32x4 oacc[16];
#pragma unroll
  for (int nt = 0; nt < 16; ++nt) oacc[nt] = (f32x4){0.f, 0.f, 0.f, 0.f};

  const int nch = q0 / 32 + 2;
  for (int ch = 0; ch < nch; ++ch) {
    const int t0 = ch * 32;
#pragma unroll
    for (int rep = 0; rep < 4; ++rep) {
      int u = rep * 256 + tid;
      int t = u >> 5;
      int d = (u & 31) * 8;
      s16x8 v = *(const s16x8*)(kvbf + (size_t)(t0 + t) * HD + d);
      *(s16x8*)&kv_s[t * 264 + d] = v;
    }
    {
      int t = tid & 31, d0 = (tid >> 5) * 32;
      const unsigned short* src = kvbf + (size_t)(t0 + t) * HD + d0;
#pragma unroll
      for (int u = 0; u < 4; ++u) {
        s16x8 v = *(const s16x8*)(src + u * 8);
#pragma unroll
        for (int j = 0; j < 8; ++j)
          kvT_s[(d0 + u * 8 + j) * 40 + t] = (unsigned short)v[j];
      }
    }
    __syncthreads();

    f32x4 sc[2];
    sc[0] = (f32x4){0.f, 0.f, 0.f, 0.f};
    sc[1] = (f32x4){0.f, 0.f, 0.f, 0.f};
#pragma unroll
    for (int ko = 0; ko < 8; ++ko) {
#pragma unroll
      for (int kt = 0; kt < 2; ++kt) {
        s16x8 bf = *(const s16x8*)&kv_s[(kt * 16 + col) * 264 + ko * 32 + grp * 8];
        sc[kt] = __builtin_amdgcn_mfma_f32_16x16x32_bf16(
            __builtin_bit_cast(bf16x8, qf[ko]), __builtin_bit_cast(bf16x8, bf),
            sc[kt], 0, 0, 0);
      }
    }
#pragma unroll
    for (int kt = 0; kt < 2; ++kt)
#pragma unroll
      for (int r = 0; r < 4; ++r) {
        int tg = t0 + kt * 16 + col;
        int sg = qrow_base + grp * 4 + r;
        float v = sc[kt][r] * SCALE;
        sc[kt][r] = (tg <= sg) ? v : -1e30f;
      }
    float alpha[4];
#pragma unroll
    for (int r = 0; r < 4; ++r) {
      float v = fmaxf(sc[0][r], sc[1][r]);
      v = fmaxf(v, __shfl_xor(v, 1));
      v = fmaxf(v, __shfl_xor(v, 2));
      v = fmaxf(v, __shfl_xor(v, 4));
      v = fmaxf(v, __shfl_xor(v, 8));
      float mn = fmaxf(m_i[r], v);
      alpha[r] = __expf(m_i[r] - mn);
      m_i[r] = mn;
    }
    float rs[4] = {0.f, 0.f, 0.f, 0.f};
#pragma unroll
    for (int kt = 0; kt < 2; ++kt)
#pragma unroll
      for (int r = 0; r < 4; ++r) {
        float p = __expf(sc[kt][r] - m_i[r]);
        rs[r] += p;
        p_s[(wave * 16 + grp * 4 + r) * 40 + kt * 16 + col] = f2bf(p);
      }
#pragma unroll
    for (int r = 0; r < 4; ++r) {
      float v = rs[r];
      v += __shfl_xor(v, 1);
      v += __shfl_xor(v, 2);
      v += __shfl_xor(v, 4);
      v += __shfl_xor(v, 8);
      l_i[r] = l_i[r] * alpha[r] + v;
#pragma unroll
      for (int nt = 0; nt < 16; ++nt) oacc[nt][r] *= alpha[r];
    }
    __syncthreads();

    s16x8 pf = *(const s16x8*)&p_s[(wave * 16 + col) * 40 + grp * 8];
#pragma unroll
    for (int nt = 0; nt < 16; ++nt) {
      s16x8 vf = *(const s16x8*)&kvT_s[(nt * 16 + col) * 40 + grp * 8];
      oacc[nt] = __builtin_amdgcn_mfma_f32_16x16x32_bf16(
          __builtin_bit_cast(bf16x8, pf), __builtin_bit_cast(bf16x8, vf),
          oacc[nt], 0, 0, 0);
    }
    __syncthreads();
  }

  const float sk = sink[h];
  float inv[4];
#pragma unroll
  for (int r = 0; r < 4; ++r) inv[r] = 1.f / (l_i[r] + __expf(sk - m_i[r]));
#pragma unroll
  for (int nt = 0; nt < 16; ++nt) {
#pragma unroll
    for (int r = 0; r < 4; ++r) {
      float v = oacc[nt][r] * inv[r];
      int srow = qrow_base + grp * 4 + r;
      if (nt >= 12) {
        int dim = nt * 16 + col;
        int j = (dim - NOPE) >> 1;
        float f = freqs[(size_t)srow * (NROT / 2) + j];
        float c = cosf(f), si = sinf(f);
        float prt = __shfl_xor(v, 1);
        v = (col & 1) ? (v * c - prt * si) : (v * c + prt * si);
      }
      ob[(size_t)srow * (NH * HD) + (size_t)h * HD + nt * 16 + col] = f2bf(v);
    }
  }
}

extern "C" void kernel_launch(void* const* d_in, const int* in_sizes, int n_in,
                              void* d_out, int out_size, void* d_ws, size_t ws_size,
                              hipStream_t stream) {
  const float* x         = (const float*)d_in[0];
  const float* freqs     = (const float*)d_in[1];
  const float* wq_a      = (const float*)d_in[2];
  const float* q_norm_w  = (const float*)d_in[3];
  const float* wq_b      = (const float*)d_in[4];
  const float* wkv       = (const float*)d_in[5];
  const float* kv_norm_w = (const float*)d_in[6];
  const float* wo_a_w    = (const float*)d_in[7];
  const float* wo_b      = (const float*)d_in[8];
  const float* sink      = (const float*)d_in[9];
  float* out = (float*)d_out;

  // Workspace (byte offsets, 54 MB total). Sizes: wo_b is 2048x2048 = 4M elems
  // = 8MB bf16 (R4 bug: converted only 1M elems into a 2MB slot).
  //  [0,4M)    qa_bf
  //  [4M,20M)  q_bf (G2 out -> attn). After attn: orb_bf [4M,12M), wob_bf [12M,20M)
  //            (wo_b converted AFTER attn, when q_bf is dead).
  //  [20M,36M) o_bf (attn out); x_bf [20M,28M) dead before attn writes.
  //  [36M,40M) wqa_bf  [40M,48M) wqb_bf  [48M,49M) wkv_bf
  //  [49M,53M) woa_bf  [53M,54M) kv_bf
  char* ws = (char*)d_ws;
  const size_t MB = 1024 * 1024;
  unsigned short* qa_bf   = (unsigned short*)(ws + 0 * MB);
  unsigned short* q_bf    = (unsigned short*)(ws + 4 * MB);
  unsigned short* orb_bf  = (unsigned short*)(ws + 4 * MB);
  unsigned short* wob_bf  = (unsigned short*)(ws + 12 * MB);
  unsigned short* o_bf    = (unsigned short*)(ws + 20 * MB);
  unsigned short* x_bf    = (unsigned short*)(ws + 20 * MB);
  unsigned short* wqa_bf  = (unsigned short*)(ws + 36 * MB);
  unsigned short* wqb_bf  = (unsigned short*)(ws + 40 * MB);
  unsigned short* wkv_bf  = (unsigned short*)(ws + 48 * MB);
  unsigned short* woa_bf  = (unsigned short*)(ws + 49 * MB);
  unsigned short* kv_bf   = (unsigned short*)(ws + 53 * MB);

  dim3 blk(256);

  // 0) fp32 -> bf16 conversions (wo_b deferred until after attention)
  f32_to_bf16<<<dim3(4096), blk, 0, stream>>>(x,      x_bf,   4 * 1024 * 1024 / 4);
  f32_to_bf16<<<dim3(2048), blk, 0, stream>>>(wq_a,   wqa_bf, 2 * 1024 * 1024 / 4);
  f32_to_bf16<<<dim3(4096), blk, 0, stream>>>(wq_b,   wqb_bf, 4 * 1024 * 1024 / 4);
  f32_to_bf16<<<dim3(512),  blk, 0, stream>>>(wkv,    wkv_bf, 512 * 1024 / 4);
  f32_to_bf16<<<dim3(2048), blk, 0, stream>>>(wo_a_w, woa_bf, 2 * 1024 * 1024 / 4);

  // 1) qa = x @ wq_a^T  (2048x1024, K=2048) -> bf16
  gemm_bf16<<<dim3(QL / 128, S_LEN / 128, 1), blk, 0, stream>>>(
      x_bf, wqa_bf, qa_bf, HID, HID, HID, QL, 0, 0, 0, 1);
  // 2) RMS in-place
  rmsnorm_bf_ip<<<dim3(S_LEN), blk, 0, stream>>>(qa_bf, q_norm_w, QL);
  // 3) q = qa @ wq_b^T  (2048x4096, K=1024) -> bf16
  gemm_bf16<<<dim3(NH * HD / 128, S_LEN / 128, 1), blk, 0, stream>>>(
      qa_bf, wqb_bf, q_bf, QL, QL, QL, NH * HD, 0, 0, 0, 1);
  // 4) per-(s,h) RMS + RoPE in-place
  qnorm_rope_ip<<<dim3(S_LEN * NH), blk, 0, stream>>>(q_bf, freqs);
  // 5) kv = x @ wkv^T   (2048x256, K=2048) -> bf16
  gemm_bf16<<<dim3(HD / 128, S_LEN / 128, 1), blk, 0, stream>>>(
      x_bf, wkv_bf, kv_bf, HID, HID, HID, HD, 0, 0, 0, 1);
  // 6) RMS + RoPE in-place
  kvnorm_rope_ip<<<dim3(S_LEN), blk, 0, stream>>>(kv_bf, kv_norm_w, freqs);
  // 7) flash attention -> o_bf
  attn_mfma<<<dim3(S_LEN / 64, NH), blk, 0, stream>>>(q_bf, kv_bf, sink, freqs, o_bf);
  // 7b) convert wo_b into [12M,20M) — q_bf dead after attention
  f32_to_bf16<<<dim3(4096), blk, 0, stream>>>(wo_b, wob_bf, 4 * 1024 * 1024 / 4);
  // 8) grouped projection via z-grid: per g, orb[:, g*512:] = o[:, g*1024:] @ wo_a[g]^T
  gemm_bf16<<<dim3(OR_ / 128, S_LEN / 128, NG), blk, 0, stream>>>(
      o_bf, woa_bf, orb_bf, HPG * HD, NH * HD, HPG * HD, NG * OR_,
      (long)(HPG * HD), (long)OR_ * (HPG * HD), (long)OR_, 1);
  // 9) out = orb @ wo_b^T (2048x2048, K=2048) -> fp32
  gemm_bf16<<<dim3(HID / 128, S_LEN / 128, 1), blk, 0, stream>>>(
      orb_bf, wob_bf, out, NG * OR_, NG * OR_, NG * OR_, HID, 0, 0, 0, 0);
}

// Round 6
// 921.944 us; speedup vs baseline: 7.4053x; 1.0035x over previous
//
#include <hip/hip_runtime.h>
#include <hip/hip_bf16.h>

// Problem constants (B=1)
#define S_LEN 2048
#define HID 2048
#define NH 16
#define HD 256
#define NROT 64
#define NOPE 192
#define QL 1024
#define OR_ 512
#define NG 4
#define HPG 4
#define EPS 1e-6f
#define SCALE 0.0625f   // 256^-0.5

typedef __bf16 bf16x8 __attribute__((ext_vector_type(8)));
typedef short s16x8 __attribute__((ext_vector_type(8)));
typedef float f32x4 __attribute__((ext_vector_type(4)));

__device__ __forceinline__ unsigned short f2bf(float x) {
  unsigned int u = __builtin_bit_cast(unsigned int, x);
  u += 0x7FFFu + ((u >> 16) & 1u);   // RNE
  return (unsigned short)(u >> 16);
}
__device__ __forceinline__ float bf2f(unsigned short b) {
  unsigned int u = ((unsigned int)b) << 16;
  return __builtin_bit_cast(float, u);
}

// ---------------- fp32 -> bf16 convert (vectorized) ----------------
__global__ __launch_bounds__(256) void f32_to_bf16(const float* __restrict__ in,
                                                   unsigned short* __restrict__ out, int n4) {
  int i = blockIdx.x * 256 + threadIdx.x;
  if (i < n4) {
    float4 v = ((const float4*)in)[i];
    ushort4 o;
    o.x = f2bf(v.x); o.y = f2bf(v.y); o.z = f2bf(v.z); o.w = f2bf(v.w);
    ((ushort4*)out)[i] = o;
  }
}

// ---------------- bf16 MFMA GEMM: C[M,N] = A[M,K] @ B[N,K]^T ----------------
// 128x128 tile, BK=32, 4 waves in 2x2, each wave 64x64 via 4x4 of 16x16x32 MFMA.
__global__ __launch_bounds__(256, 2) void gemm_bf16(
    const unsigned short* __restrict__ A, const unsigned short* __restrict__ B,
    void* __restrict__ Cv, int K, int lda, int ldb, int ldc,
    long aoffz, long boffz, long coffz, int store_bf) {
  __shared__ __align__(16) unsigned short As[128 * 40];
  __shared__ __align__(16) unsigned short Bs[128 * 40];
  A += (size_t)blockIdx.z * aoffz;
  B += (size_t)blockIdx.z * boffz;
  const int tid = threadIdx.x;
  const int wave = tid >> 6, lane = tid & 63;
  const int col = lane & 15, grp = lane >> 4;
  const int wm = wave >> 1, wn = wave & 1;
  const int m0 = blockIdx.y * 128, n0 = blockIdx.x * 128;

  f32x4 acc[4][4];
#pragma unroll
  for (int i = 0; i < 4; ++i)
#pragma unroll
    for (int j = 0; j < 4; ++j) acc[i][j] = (f32x4){0.f, 0.f, 0.f, 0.f};

  for (int k0 = 0; k0 < K; k0 += 32) {
#pragma unroll
    for (int u = 0; u < 2; ++u) {
      int lin = u * 256 + tid;
      int r = lin >> 2, c8 = (lin & 3) * 8;
      *(s16x8*)&As[r * 40 + c8] = *(const s16x8*)(A + (size_t)(m0 + r) * lda + k0 + c8);
      *(s16x8*)&Bs[r * 40 + c8] = *(const s16x8*)(B + (size_t)(n0 + r) * ldb + k0 + c8);
    }
    __syncthreads();
    s16x8 a[4], b[4];
#pragma unroll
    for (int i = 0; i < 4; ++i)
      a[i] = *(const s16x8*)&As[(wm * 64 + i * 16 + col) * 40 + grp * 8];
#pragma unroll
    for (int j = 0; j < 4; ++j)
      b[j] = *(const s16x8*)&Bs[(wn * 64 + j * 16 + col) * 40 + grp * 8];
#pragma unroll
    for (int i = 0; i < 4; ++i)
#pragma unroll
      for (int j = 0; j < 4; ++j)
        acc[i][j] = __builtin_amdgcn_mfma_f32_16x16x32_bf16(
            __builtin_bit_cast(bf16x8, a[i]), __builtin_bit_cast(bf16x8, b[j]),
            acc[i][j], 0, 0, 0);
    __syncthreads();
  }

  if (store_bf) {
    unsigned short* C = (unsigned short*)Cv + (size_t)blockIdx.z * coffz;
#pragma unroll
    for (int i = 0; i < 4; ++i)
#pragma unroll
      for (int j = 0; j < 4; ++j)
#pragma unroll
        for (int r = 0; r < 4; ++r)
          C[(size_t)(m0 + wm * 64 + i * 16 + grp * 4 + r) * ldc +
            n0 + wn * 64 + j * 16 + col] = f2bf(acc[i][j][r]);
  } else {
    float* C = (float*)Cv + (size_t)blockIdx.z * coffz;
#pragma unroll
    for (int i = 0; i < 4; ++i)
#pragma unroll
      for (int j = 0; j < 4; ++j)
#pragma unroll
        for (int r = 0; r < 4; ++r)
          C[(size_t)(m0 + wm * 64 + i * 16 + grp * 4 + r) * ldc +
            n0 + wn * 64 + j * 16 + col] = acc[i][j][r];
  }
}

// ---------------- RMSNorm (weighted) in-place on bf16 rows of length L ----------------
__global__ __launch_bounds__(256) void rmsnorm_bf_ip(unsigned short* __restrict__ x,
                                                     const float* __restrict__ w, int L) {
  int row = blockIdx.x;
  unsigned short* p = x + (size_t)row * L;
  __shared__ float red[256];
  float s = 0.f;
  for (int i = threadIdx.x; i < L; i += 256) { float v = bf2f(p[i]); s += v * v; }
  red[threadIdx.x] = s;
  __syncthreads();
  for (int off = 128; off > 0; off >>= 1) {
    if (threadIdx.x < off) red[threadIdx.x] += red[threadIdx.x + off];
    __syncthreads();
  }
  float r = rsqrtf(red[0] / (float)L + EPS);
  for (int i = threadIdx.x; i < L; i += 256) p[i] = f2bf(bf2f(p[i]) * r * w[i]);
}

// ---------------- Q per-head RMS (no weight) + RoPE, in-place bf16 ----------------
__global__ __launch_bounds__(256) void qnorm_rope_ip(unsigned short* __restrict__ q,
                                                     const float* __restrict__ freqs) {
  int row = blockIdx.x;       // s*NH + h
  int s = row / NH;
  unsigned short* p = q + (size_t)row * HD;
  int d = threadIdx.x;
  float v = bf2f(p[d]);
  __shared__ float red[256];
  __shared__ float sm[256];
  red[d] = v * v;
  __syncthreads();
  for (int off = 128; off > 0; off >>= 1) {
    if (d < off) red[d] += red[d + off];
    __syncthreads();
  }
  float r = rsqrtf(red[0] / 256.0f + EPS);
  float nv = v * r;
  sm[d] = nv;
  __syncthreads();
  float outv = nv;
  if (d >= NOPE) {
    int j = (d - NOPE) >> 1;
    float f = freqs[(size_t)s * (NROT / 2) + j];
    float c = cosf(f), si = sinf(f);
    float x1 = sm[NOPE + 2 * j], x2 = sm[NOPE + 2 * j + 1];
    outv = ((d & 1) == 0) ? (x1 * c - x2 * si) : (x1 * si + x2 * c);
  }
  p[d] = f2bf(outv);
}

// ---------------- KV RMS (weighted) + RoPE, in-place bf16 ----------------
__global__ __launch_bounds__(256) void kvnorm_rope_ip(unsigned short* __restrict__ kv,
                                                      const float* __restrict__ w,
                                                      const float* __restrict__ freqs) {
  int s = blockIdx.x;
  unsigned short* p = kv + (size_t)s * HD;
  int d = threadIdx.x;
  float v = bf2f(p[d]);
  __shared__ float red[256];
  __shared__ float sm[256];
  red[d] = v * v;
  __syncthreads();
  for (int off = 128; off > 0; off >>= 1) {
    if (d < off) red[d] += red[d + off];
    __syncthreads();
  }
  float r = rsqrtf(red[0] / 256.0f + EPS);
  float nv = v * r * w[d];
  sm[d] = nv;
  __syncthreads();
  float outv = nv;
  if (d >= NOPE) {
    int j = (d - NOPE) >> 1;
    float f = freqs[(size_t)s * (NROT / 2) + j];
    float c = cosf(f), si = sinf(f);
    float x1 = sm[NOPE + 2 * j], x2 = sm[NOPE + 2 * j + 1];
    outv = ((d & 1) == 0) ? (x1 * c - x2 * si) : (x1 * si + x2 * c);
  }
  p[d] = f2bf(outv);
}

// ---------------- MFMA flash attention (bf16 out) ----------------
// R5 post-mortem: qf register tile + oacc pushed waves past the 256-unified-reg
// boundary -> 1 wave/SIMD + per-iter oacc spill (946 MB HBM writes). Fix: Q tile
// lives in LDS (read per-MFMA via ds_read_b128), __launch_bounds__(256,2)
// forces <=256 regs/wave. Persistent regs now ~180 incl. 64 acc.
__global__ __launch_bounds__(256, 2) void attn_mfma(
    const unsigned short* __restrict__ qbf,   // (S, NH*HD) bf16
    const unsigned short* __restrict__ kvbf,  // (S, HD) bf16
    const float* __restrict__ sink,
    const float* __restrict__ freqs,
    unsigned short* __restrict__ ob) {        // (S, NH*HD) bf16
  __shared__ __align__(16) unsigned short q_s[64 * 264];     // [row][d]
  __shared__ __align__(16) unsigned short kv_s[32 * 264];    // [t][d]
  __shared__ __align__(16) unsigned short kvT_s[256 * 40];   // [d][t]
  __shared__ __align__(16) unsigned short p_s[64 * 40];      // [row][t]

  const int tid = threadIdx.x;
  const int wave = tid >> 6, lane = tid & 63;
  const int col = lane & 15, grp = lane >> 4;
  const int q0 = (gridDim.x - 1 - blockIdx.x) * 64;   // big tiles first (LPT)
  const int h = blockIdx.y;
  const int qrow_base = q0 + wave * 16;

  // Stage Q tile 64x256 into LDS once (first K-loop barrier fences it).
#pragma unroll
  for (int u = 0; u < 8; ++u) {
    int lin = u * 256 + tid;
    int r = lin >> 5;            // 32 x 16B units per row
    int dq = (lin & 31) * 8;
    *(s16x8*)&q_s[r * 264 + dq] =
        *(const s16x8*)(qbf + (size_t)(q0 + r) * (NH * HD) + (size_t)h * HD + dq);
  }

  float m_i[4], l_i[4];
#pragma unroll
  for (int r = 0; r < 4; ++r) { m_i[r] = -1e30f; l_i[r] = 0.f; }
  f32x4 oacc[16];
#pragma unroll
  for (int nt = 0; nt < 16; ++nt) oacc[nt] = (f32x4){0.f, 0.f, 0.f, 0.f};

  const int nch = q0 / 32 + 2;
  for (int ch = 0; ch < nch; ++ch) {
    const int t0 = ch * 32;
#pragma unroll
    for (int rep = 0; rep < 4; ++rep) {
      int u = rep * 256 + tid;
      int t = u >> 5;
      int d = (u & 31) * 8;
      s16x8 v = *(const s16x8*)(kvbf + (size_t)(t0 + t) * HD + d);
      *(s16x8*)&kv_s[t * 264 + d] = v;
    }
    {
      int t = tid & 31, d0 = (tid >> 5) * 32;
      const unsigned short* src = kvbf + (size_t)(t0 + t) * HD + d0;
#pragma unroll
      for (int u = 0; u < 4; ++u) {
        s16x8 v = *(const s16x8*)(src + u * 8);
#pragma unroll
        for (int j = 0; j < 8; ++j)
          kvT_s[(d0 + u * 8 + j) * 40 + t] = (unsigned short)v[j];
      }
    }
    __syncthreads();

    f32x4 sc[2];
    sc[0] = (f32x4){0.f, 0.f, 0.f, 0.f};
    sc[1] = (f32x4){0.f, 0.f, 0.f, 0.f};
#pragma unroll
    for (int ko = 0; ko < 8; ++ko) {
      s16x8 af = *(const s16x8*)&q_s[(wave * 16 + col) * 264 + ko * 32 + grp * 8];
#pragma unroll
      for (int kt = 0; kt < 2; ++kt) {
        s16x8 bf = *(const s16x8*)&kv_s[(kt * 16 + col) * 264 + ko * 32 + grp * 8];
        sc[kt] = __builtin_amdgcn_mfma_f32_16x16x32_bf16(
            __builtin_bit_cast(bf16x8, af), __builtin_bit_cast(bf16x8, bf),
            sc[kt], 0, 0, 0);
      }
    }
#pragma unroll
    for (int kt = 0; kt < 2; ++kt)
#pragma unroll
      for (int r = 0; r < 4; ++r) {
        int tg = t0 + kt * 16 + col;
        int sg = qrow_base + grp * 4 + r;
        float v = sc[kt][r] * SCALE;
        sc[kt][r] = (tg <= sg) ? v : -1e30f;
      }
    float alpha[4];
#pragma unroll
    for (int r = 0; r < 4; ++r) {
      float v = fmaxf(sc[0][r], sc[1][r]);
      v = fmaxf(v, __shfl_xor(v, 1));
      v = fmaxf(v, __shfl_xor(v, 2));
      v = fmaxf(v, __shfl_xor(v, 4));
      v = fmaxf(v, __shfl_xor(v, 8));
      float mn = fmaxf(m_i[r], v);
      alpha[r] = __expf(m_i[r] - mn);
      m_i[r] = mn;
    }
    float rs[4] = {0.f, 0.f, 0.f, 0.f};
#pragma unroll
    for (int kt = 0; kt < 2; ++kt)
#pragma unroll
      for (int r = 0; r < 4; ++r) {
        float p = __expf(sc[kt][r] - m_i[r]);
        rs[r] += p;
        p_s[(wave * 16 + grp * 4 + r) * 40 + kt * 16 + col] = f2bf(p);
      }
#pragma unroll
    for (int r = 0; r < 4; ++r) {
      float v = rs[r];
      v += __shfl_xor(v, 1);
      v += __shfl_xor(v, 2);
      v += __shfl_xor(v, 4);
      v += __shfl_xor(v, 8);
      l_i[r] = l_i[r] * alpha[r] + v;
#pragma unroll
      for (int nt = 0; nt < 16; ++nt) oacc[nt][r] *= alpha[r];
    }
    __syncthreads();

    s16x8 pf = *(const s16x8*)&p_s[(wave * 16 + col) * 40 + grp * 8];
#pragma unroll
    for (int nt = 0; nt < 16; ++nt) {
      s16x8 vf = *(const s16x8*)&kvT_s[(nt * 16 + col) * 40 + grp * 8];
      oacc[nt] = __builtin_amdgcn_mfma_f32_16x16x32_bf16(
          __builtin_bit_cast(bf16x8, pf), __builtin_bit_cast(bf16x8, vf),
          oacc[nt], 0, 0, 0);
    }
    __syncthreads();
  }

  const float sk = sink[h];
  float inv[4];
#pragma unroll
  for (int r = 0; r < 4; ++r) inv[r] = 1.f / (l_i[r] + __expf(sk - m_i[r]));
#pragma unroll
  for (int nt = 0; nt < 16; ++nt) {
#pragma unroll
    for (int r = 0; r < 4; ++r) {
      float v = oacc[nt][r] * inv[r];
      int srow = qrow_base + grp * 4 + r;
      if (nt >= 12) {
        int dim = nt * 16 + col;
        int j = (dim - NOPE) >> 1;
        float f = freqs[(size_t)srow * (NROT / 2) + j];
        float c = cosf(f), si = sinf(f);
        float prt = __shfl_xor(v, 1);
        v = (col & 1) ? (v * c - prt * si) : (v * c + prt * si);
      }
      ob[(size_t)srow * (NH * HD) + (size_t)h * HD + nt * 16 + col] = f2bf(v);
    }
  }
}

extern "C" void kernel_launch(void* const* d_in, const int* in_sizes, int n_in,
                              void* d_out, int out_size, void* d_ws, size_t ws_size,
                              hipStream_t stream) {
  const float* x         = (const float*)d_in[0];
  const float* freqs     = (const float*)d_in[1];
  const float* wq_a      = (const float*)d_in[2];
  const float* q_norm_w  = (const float*)d_in[3];
  const float* wq_b      = (const float*)d_in[4];
  const float* wkv       = (const float*)d_in[5];
  const float* kv_norm_w = (const float*)d_in[6];
  const float* wo_a_w    = (const float*)d_in[7];
  const float* wo_b      = (const float*)d_in[8];
  const float* sink      = (const float*)d_in[9];
  float* out = (float*)d_out;

  // Workspace (byte offsets, 54 MB total):
  //  [0,4M)    qa_bf
  //  [4M,20M)  q_bf (G2 out -> attn). After attn: orb_bf [4M,12M), wob_bf [12M,20M)
  //  [20M,36M) o_bf (attn out); x_bf [20M,28M) dead before attn writes.
  //  [36M,40M) wqa_bf  [40M,48M) wqb_bf  [48M,49M) wkv_bf
  //  [49M,53M) woa_bf  [53M,54M) kv_bf
  char* ws = (char*)d_ws;
  const size_t MB = 1024 * 1024;
  unsigned short* qa_bf   = (unsigned short*)(ws + 0 * MB);
  unsigned short* q_bf    = (unsigned short*)(ws + 4 * MB);
  unsigned short* orb_bf  = (unsigned short*)(ws + 4 * MB);
  unsigned short* wob_bf  = (unsigned short*)(ws + 12 * MB);
  unsigned short* o_bf    = (unsigned short*)(ws + 20 * MB);
  unsigned short* x_bf    = (unsigned short*)(ws + 20 * MB);
  unsigned short* wqa_bf  = (unsigned short*)(ws + 36 * MB);
  unsigned short* wqb_bf  = (unsigned short*)(ws + 40 * MB);
  unsigned short* wkv_bf  = (unsigned short*)(ws + 48 * MB);
  unsigned short* woa_bf  = (unsigned short*)(ws + 49 * MB);
  unsigned short* kv_bf   = (unsigned short*)(ws + 53 * MB);

  dim3 blk(256);

  // 0) fp32 -> bf16 conversions (wo_b deferred until after attention)
  f32_to_bf16<<<dim3(4096), blk, 0, stream>>>(x,      x_bf,   4 * 1024 * 1024 / 4);
  f32_to_bf16<<<dim3(2048), blk, 0, stream>>>(wq_a,   wqa_bf, 2 * 1024 * 1024 / 4);
  f32_to_bf16<<<dim3(4096), blk, 0, stream>>>(wq_b,   wqb_bf, 4 * 1024 * 1024 / 4);
  f32_to_bf16<<<dim3(512),  blk, 0, stream>>>(wkv,    wkv_bf, 512 * 1024 / 4);
  f32_to_bf16<<<dim3(2048), blk, 0, stream>>>(wo_a_w, woa_bf, 2 * 1024 * 1024 / 4);

  // 1) qa = x @ wq_a^T  (2048x1024, K=2048) -> bf16
  gemm_bf16<<<dim3(QL / 128, S_LEN / 128, 1), blk, 0, stream>>>(
      x_bf, wqa_bf, qa_bf, HID, HID, HID, QL, 0, 0, 0, 1);
  // 2) RMS in-place
  rmsnorm_bf_ip<<<dim3(S_LEN), blk, 0, stream>>>(qa_bf, q_norm_w, QL);
  // 3) q = qa @ wq_b^T  (2048x4096, K=1024) -> bf16
  gemm_bf16<<<dim3(NH * HD / 128, S_LEN / 128, 1), blk, 0, stream>>>(
      qa_bf, wqb_bf, q_bf, QL, QL, QL, NH * HD, 0, 0, 0, 1);
  // 4) per-(s,h) RMS + RoPE in-place
  qnorm_rope_ip<<<dim3(S_LEN * NH), blk, 0, stream>>>(q_bf, freqs);
  // 5) kv = x @ wkv^T   (2048x256, K=2048) -> bf16
  gemm_bf16<<<dim3(HD / 128, S_LEN / 128, 1), blk, 0, stream>>>(
      x_bf, wkv_bf, kv_bf, HID, HID, HID, HD, 0, 0, 0, 1);
  // 6) RMS + RoPE in-place
  kvnorm_rope_ip<<<dim3(S_LEN), blk, 0, stream>>>(kv_bf, kv_norm_w, freqs);
  // 7) flash attention -> o_bf
  attn_mfma<<<dim3(S_LEN / 64, NH), blk, 0, stream>>>(q_bf, kv_bf, sink, freqs, o_bf);
  // 7b) convert wo_b into [12M,20M) — q_bf dead after attention
  f32_to_bf16<<<dim3(4096), blk, 0, stream>>>(wo_b, wob_bf, 4 * 1024 * 1024 / 4);
  // 8) grouped projection via z-grid
  gemm_bf16<<<dim3(OR_ / 128, S_LEN / 128, NG), blk, 0, stream>>>(
      o_bf, woa_bf, orb_bf, HPG * HD, NH * HD, HPG * HD, NG * OR_,
      (long)(HPG * HD), (long)OR_ * (HPG * HD), (long)OR_, 1);
  // 9) out = orb @ wo_b^T (2048x2048, K=2048) -> fp32
  gemm_bf16<<<dim3(HID / 128, S_LEN / 128, 1), blk, 0, stream>>>(
      orb_bf, wob_bf, out, NG * OR_, NG * OR_, NG * OR_, HID, 0, 0, 0, 0);
}

// Round 7
// 539.831 us; speedup vs baseline: 12.6471x; 1.7078x over previous
//
#include <hip/hip_runtime.h>
#include <hip/hip_bf16.h>

// Problem constants (B=1)
#define S_LEN 2048
#define HID 2048
#define NH 16
#define HD 256
#define NROT 64
#define NOPE 192
#define QL 1024
#define OR_ 512
#define NG 4
#define HPG 4
#define EPS 1e-6f
#define SCALE 0.0625f   // 256^-0.5

typedef __bf16 bf16x8 __attribute__((ext_vector_type(8)));
typedef short s16x8 __attribute__((ext_vector_type(8)));
typedef float f32x4 __attribute__((ext_vector_type(4)));

__device__ __forceinline__ unsigned short f2bf(float x) {
  unsigned int u = __builtin_bit_cast(unsigned int, x);
  u += 0x7FFFu + ((u >> 16) & 1u);   // RNE
  return (unsigned short)(u >> 16);
}
__device__ __forceinline__ float bf2f(unsigned short b) {
  unsigned int u = ((unsigned int)b) << 16;
  return __builtin_bit_cast(float, u);
}

// ---------------- fp32 -> bf16 convert (vectorized) ----------------
__global__ __launch_bounds__(256) void f32_to_bf16(const float* __restrict__ in,
                                                   unsigned short* __restrict__ out, int n4) {
  int i = blockIdx.x * 256 + threadIdx.x;
  if (i < n4) {
    float4 v = ((const float4*)in)[i];
    ushort4 o;
    o.x = f2bf(v.x); o.y = f2bf(v.y); o.z = f2bf(v.z); o.w = f2bf(v.w);
    ((ushort4*)out)[i] = o;
  }
}

// ---------------- bf16 MFMA GEMM: C[M,N] = A[M,K] @ B[N,K]^T ----------------
__global__ __launch_bounds__(256, 2) void gemm_bf16(
    const unsigned short* __restrict__ A, const unsigned short* __restrict__ B,
    void* __restrict__ Cv, int K, int lda, int ldb, int ldc,
    long aoffz, long boffz, long coffz, int store_bf) {
  __shared__ __align__(16) unsigned short As[128 * 40];
  __shared__ __align__(16) unsigned short Bs[128 * 40];
  A += (size_t)blockIdx.z * aoffz;
  B += (size_t)blockIdx.z * boffz;
  const int tid = threadIdx.x;
  const int wave = tid >> 6, lane = tid & 63;
  const int col = lane & 15, grp = lane >> 4;
  const int wm = wave >> 1, wn = wave & 1;
  const int m0 = blockIdx.y * 128, n0 = blockIdx.x * 128;

  f32x4 acc[4][4];
#pragma unroll
  for (int i = 0; i < 4; ++i)
#pragma unroll
    for (int j = 0; j < 4; ++j) acc[i][j] = (f32x4){0.f, 0.f, 0.f, 0.f};

  for (int k0 = 0; k0 < K; k0 += 32) {
#pragma unroll
    for (int u = 0; u < 2; ++u) {
      int lin = u * 256 + tid;
      int r = lin >> 2, c8 = (lin & 3) * 8;
      *(s16x8*)&As[r * 40 + c8] = *(const s16x8*)(A + (size_t)(m0 + r) * lda + k0 + c8);
      *(s16x8*)&Bs[r * 40 + c8] = *(const s16x8*)(B + (size_t)(n0 + r) * ldb + k0 + c8);
    }
    __syncthreads();
    s16x8 a[4], b[4];
#pragma unroll
    for (int i = 0; i < 4; ++i)
      a[i] = *(const s16x8*)&As[(wm * 64 + i * 16 + col) * 40 + grp * 8];
#pragma unroll
    for (int j = 0; j < 4; ++j)
      b[j] = *(const s16x8*)&Bs[(wn * 64 + j * 16 + col) * 40 + grp * 8];
#pragma unroll
    for (int i = 0; i < 4; ++i)
#pragma unroll
      for (int j = 0; j < 4; ++j)
        acc[i][j] = __builtin_amdgcn_mfma_f32_16x16x32_bf16(
            __builtin_bit_cast(bf16x8, a[i]), __builtin_bit_cast(bf16x8, b[j]),
            acc[i][j], 0, 0, 0);
    __syncthreads();
  }

  if (store_bf) {
    unsigned short* C = (unsigned short*)Cv + (size_t)blockIdx.z * coffz;
#pragma unroll
    for (int i = 0; i < 4; ++i)
#pragma unroll
      for (int j = 0; j < 4; ++j)
#pragma unroll
        for (int r = 0; r < 4; ++r)
          C[(size_t)(m0 + wm * 64 + i * 16 + grp * 4 + r) * ldc +
            n0 + wn * 64 + j * 16 + col] = f2bf(acc[i][j][r]);
  } else {
    float* C = (float*)Cv + (size_t)blockIdx.z * coffz;
#pragma unroll
    for (int i = 0; i < 4; ++i)
#pragma unroll
      for (int j = 0; j < 4; ++j)
#pragma unroll
        for (int r = 0; r < 4; ++r)
          C[(size_t)(m0 + wm * 64 + i * 16 + grp * 4 + r) * ldc +
            n0 + wn * 64 + j * 16 + col] = acc[i][j][r];
  }
}

// ---------------- RMSNorm (weighted) in-place on bf16 rows of length L ----------------
__global__ __launch_bounds__(256) void rmsnorm_bf_ip(unsigned short* __restrict__ x,
                                                     const float* __restrict__ w, int L) {
  int row = blockIdx.x;
  unsigned short* p = x + (size_t)row * L;
  __shared__ float red[256];
  float s = 0.f;
  for (int i = threadIdx.x; i < L; i += 256) { float v = bf2f(p[i]); s += v * v; }
  red[threadIdx.x] = s;
  __syncthreads();
  for (int off = 128; off > 0; off >>= 1) {
    if (threadIdx.x < off) red[threadIdx.x] += red[threadIdx.x + off];
    __syncthreads();
  }
  float r = rsqrtf(red[0] / (float)L + EPS);
  for (int i = threadIdx.x; i < L; i += 256) p[i] = f2bf(bf2f(p[i]) * r * w[i]);
}

// ---------------- Q per-head RMS (no weight) + RoPE, in-place bf16 ----------------
__global__ __launch_bounds__(256) void qnorm_rope_ip(unsigned short* __restrict__ q,
                                                     const float* __restrict__ freqs) {
  int row = blockIdx.x;       // s*NH + h
  int s = row / NH;
  unsigned short* p = q + (size_t)row * HD;
  int d = threadIdx.x;
  float v = bf2f(p[d]);
  __shared__ float red[256];
  __shared__ float sm[256];
  red[d] = v * v;
  __syncthreads();
  for (int off = 128; off > 0; off >>= 1) {
    if (d < off) red[d] += red[d + off];
    __syncthreads();
  }
  float r = rsqrtf(red[0] / 256.0f + EPS);
  float nv = v * r;
  sm[d] = nv;
  __syncthreads();
  float outv = nv;
  if (d >= NOPE) {
    int j = (d - NOPE) >> 1;
    float f = freqs[(size_t)s * (NROT / 2) + j];
    float c = cosf(f), si = sinf(f);
    float x1 = sm[NOPE + 2 * j], x2 = sm[NOPE + 2 * j + 1];
    outv = ((d & 1) == 0) ? (x1 * c - x2 * si) : (x1 * si + x2 * c);
  }
  p[d] = f2bf(outv);
}

// ---------------- KV RMS (weighted) + RoPE, in-place bf16 ----------------
__global__ __launch_bounds__(256) void kvnorm_rope_ip(unsigned short* __restrict__ kv,
                                                      const float* __restrict__ w,
                                                      const float* __restrict__ freqs) {
  int s = blockIdx.x;
  unsigned short* p = kv + (size_t)s * HD;
  int d = threadIdx.x;
  float v = bf2f(p[d]);
  __shared__ float red[256];
  __shared__ float sm[256];
  red[d] = v * v;
  __syncthreads();
  for (int off = 128; off > 0; off >>= 1) {
    if (d < off) red[d] += red[d + off];
    __syncthreads();
  }
  float r = rsqrtf(red[0] / 256.0f + EPS);
  float nv = v * r * w[d];
  sm[d] = nv;
  __syncthreads();
  float outv = nv;
  if (d >= NOPE) {
    int j = (d - NOPE) >> 1;
    float f = freqs[(size_t)s * (NROT / 2) + j];
    float c = cosf(f), si = sinf(f);
    float x1 = sm[NOPE + 2 * j], x2 = sm[NOPE + 2 * j + 1];
    outv = ((d & 1) == 0) ? (x1 * c - x2 * si) : (x1 * si + x2 * c);
  }
  p[d] = f2bf(outv);
}

// ---------------- MFMA flash attention (bf16 out) ----------------
// R6 post-mortem: WRITE_SIZE ~940 MB invariant across register allocations =>
// the addressable C arrays (oacc[16], sc[2], m_i/l_i[4]) live in scratch and
// the per-chunk alpha-rescale RMW streams ~256 B/thread/iter to HBM. This
// version has ZERO addressable arrays: all state is named SSA variables,
// all loops over them macro-expanded.
__global__ __launch_bounds__(256, 2) void attn_mfma(
    const unsigned short* __restrict__ qbf,   // (S, NH*HD) bf16
    const unsigned short* __restrict__ kvbf,  // (S, HD) bf16
    const float* __restrict__ sink,
    const float* __restrict__ freqs,
    unsigned short* __restrict__ ob) {        // (S, NH*HD) bf16
  __shared__ __align__(16) unsigned short q_s[64 * 264];     // [row][d]
  __shared__ __align__(16) unsigned short kv_s[32 * 264];    // [t][d]
  __shared__ __align__(16) unsigned short kvT_s[256 * 40];   // [d][t]
  __shared__ __align__(16) unsigned short p_s[64 * 40];      // [row][t]

  const int tid = threadIdx.x;
  const int wave = tid >> 6, lane = tid & 63;
  const int col = lane & 15, grp = lane >> 4;
  const int q0 = (gridDim.x - 1 - blockIdx.x) * 64;   // big tiles first (LPT)
  const int h = blockIdx.y;
  const int qrow_base = q0 + wave * 16;

  // Stage Q tile 64x256 into LDS once.
#pragma unroll
  for (int u = 0; u < 8; ++u) {
    int lin = u * 256 + tid;
    int r = lin >> 5;
    int dq = (lin & 31) * 8;
    *(s16x8*)&q_s[r * 264 + dq] =
        *(const s16x8*)(qbf + (size_t)(q0 + r) * (NH * HD) + (size_t)h * HD + dq);
  }

  const f32x4 z4 = (f32x4){0.f, 0.f, 0.f, 0.f};
  float m0r = -1e30f, m1r = -1e30f, m2r = -1e30f, m3r = -1e30f;
  float l0r = 0.f, l1r = 0.f, l2r = 0.f, l3r = 0.f;

#define FOR16(M) M(0, o0) M(1, o1) M(2, o2) M(3, o3) M(4, o4) M(5, o5) M(6, o6) M(7, o7) \
                 M(8, o8) M(9, o9) M(10, o10) M(11, o11) M(12, o12) M(13, o13) M(14, o14) M(15, o15)
#define DECLO(nt, onam) f32x4 onam = z4;
  FOR16(DECLO)

  const int nch = q0 / 32 + 2;
  for (int ch = 0; ch < nch; ++ch) {
    const int t0 = ch * 32;
#pragma unroll
    for (int rep = 0; rep < 4; ++rep) {
      int u = rep * 256 + tid;
      int t = u >> 5;
      int d = (u & 31) * 8;
      s16x8 v = *(const s16x8*)(kvbf + (size_t)(t0 + t) * HD + d);
      *(s16x8*)&kv_s[t * 264 + d] = v;
    }
    {
      int t = tid & 31, d0 = (tid >> 5) * 32;
      const unsigned short* src = kvbf + (size_t)(t0 + t) * HD + d0;
#pragma unroll
      for (int u = 0; u < 4; ++u) {
        s16x8 v = *(const s16x8*)(src + u * 8);
#pragma unroll
        for (int j = 0; j < 8; ++j)
          kvT_s[(d0 + u * 8 + j) * 40 + t] = (unsigned short)v[j];
      }
    }
    __syncthreads();

    // ---- QK^T: two 16x16 key tiles, named accumulators ----
    f32x4 s0 = z4, s1 = z4;
#pragma unroll
    for (int ko = 0; ko < 8; ++ko) {
      s16x8 af = *(const s16x8*)&q_s[(wave * 16 + col) * 264 + ko * 32 + grp * 8];
      s16x8 b0 = *(const s16x8*)&kv_s[(col) * 264 + ko * 32 + grp * 8];
      s16x8 b1 = *(const s16x8*)&kv_s[(16 + col) * 264 + ko * 32 + grp * 8];
      s0 = __builtin_amdgcn_mfma_f32_16x16x32_bf16(
          __builtin_bit_cast(bf16x8, af), __builtin_bit_cast(bf16x8, b0), s0, 0, 0, 0);
      s1 = __builtin_amdgcn_mfma_f32_16x16x32_bf16(
          __builtin_bit_cast(bf16x8, af), __builtin_bit_cast(bf16x8, b1), s1, 0, 0, 0);
    }

    // ---- scale + causal mask (straight-line) ----
#define MASKR(r) { int sg = qrow_base + grp * 4 + (r); \
    s0[r] = (t0 + col <= sg) ? s0[r] * SCALE : -1e30f; \
    s1[r] = (t0 + 16 + col <= sg) ? s1[r] * SCALE : -1e30f; }
    MASKR(0) MASKR(1) MASKR(2) MASKR(3)

    // ---- online softmax: row max -> alpha ----
    float a0, a1, a2, a3;
#define MAXR(r, mr, ar) { float v = fmaxf(s0[r], s1[r]); \
    v = fmaxf(v, __shfl_xor(v, 1)); v = fmaxf(v, __shfl_xor(v, 2)); \
    v = fmaxf(v, __shfl_xor(v, 4)); v = fmaxf(v, __shfl_xor(v, 8)); \
    float mn = fmaxf(mr, v); ar = __expf(mr - mn); mr = mn; }
    MAXR(0, m0r, a0) MAXR(1, m1r, a1) MAXR(2, m2r, a2) MAXR(3, m3r, a3)

    // ---- p, row-sum, write p_s ----
    float rs0, rs1, rs2, rs3;
#define PROW(r, mr, rsr) { float p0 = __expf(s0[r] - mr); float p1 = __expf(s1[r] - mr); \
    rsr = p0 + p1; \
    p_s[(wave * 16 + grp * 4 + (r)) * 40 + col] = f2bf(p0); \
    p_s[(wave * 16 + grp * 4 + (r)) * 40 + 16 + col] = f2bf(p1); }
    PROW(0, m0r, rs0) PROW(1, m1r, rs1) PROW(2, m2r, rs2) PROW(3, m3r, rs3)

#define SUMR(r, rsr, lr, ar) { float v = rsr; \
    v += __shfl_xor(v, 1); v += __shfl_xor(v, 2); \
    v += __shfl_xor(v, 4); v += __shfl_xor(v, 8); \
    lr = lr * ar + v; }
    SUMR(0, rs0, l0r, a0) SUMR(1, rs1, l1r, a1) SUMR(2, rs2, l2r, a2) SUMR(3, rs3, l3r, a3)

    // ---- rescale accumulators (vector multiply, named vars) ----
    {
      f32x4 av = (f32x4){a0, a1, a2, a3};
#define RESC(nt, onam) onam *= av;
      FOR16(RESC)
    }
    __syncthreads();

    // ---- PV: P(16x32) @ KV(32x256), named accumulators ----
    {
      s16x8 pf = *(const s16x8*)&p_s[(wave * 16 + col) * 40 + grp * 8];
#define PVOP(nt, onam) { s16x8 vf = *(const s16x8*)&kvT_s[((nt) * 16 + col) * 40 + grp * 8]; \
      onam = __builtin_amdgcn_mfma_f32_16x16x32_bf16( \
          __builtin_bit_cast(bf16x8, pf), __builtin_bit_cast(bf16x8, vf), onam, 0, 0, 0); }
      FOR16(PVOP)
    }
    __syncthreads();
  }

  // ---- epilogue: sink, normalize, conj-RoPE on dims [192,256), store ----
  const float sk = sink[h];
  const float inv0 = 1.f / (l0r + __expf(sk - m0r));
  const float inv1 = 1.f / (l1r + __expf(sk - m1r));
  const float inv2 = 1.f / (l2r + __expf(sk - m2r));
  const float inv3 = 1.f / (l3r + __expf(sk - m3r));
#define EPI1(nt, onam, r, invr) { float v = onam[r] * invr; \
    int srow = qrow_base + grp * 4 + (r); \
    if ((nt) >= 12) { int dim = (nt) * 16 + col; int j = (dim - NOPE) >> 1; \
      float f = freqs[(size_t)srow * (NROT / 2) + j]; \
      float c = cosf(f), si = sinf(f); float prt = __shfl_xor(v, 1); \
      v = (col & 1) ? (v * c - prt * si) : (v * c + prt * si); } \
    ob[(size_t)srow * (NH * HD) + (size_t)h * HD + (nt) * 16 + col] = f2bf(v); }
#define EPI(nt, onam) EPI1(nt, onam, 0, inv0) EPI1(nt, onam, 1, inv1) \
                      EPI1(nt, onam, 2, inv2) EPI1(nt, onam, 3, inv3)
  FOR16(EPI)
}

extern "C" void kernel_launch(void* const* d_in, const int* in_sizes, int n_in,
                              void* d_out, int out_size, void* d_ws, size_t ws_size,
                              hipStream_t stream) {
  const float* x         = (const float*)d_in[0];
  const float* freqs     = (const float*)d_in[1];
  const float* wq_a      = (const float*)d_in[2];
  const float* q_norm_w  = (const float*)d_in[3];
  const float* wq_b      = (const float*)d_in[4];
  const float* wkv       = (const float*)d_in[5];
  const float* kv_norm_w = (const float*)d_in[6];
  const float* wo_a_w    = (const float*)d_in[7];
  const float* wo_b      = (const float*)d_in[8];
  const float* sink      = (const float*)d_in[9];
  float* out = (float*)d_out;

  // Workspace (byte offsets, 54 MB total):
  //  [0,4M)    qa_bf
  //  [4M,20M)  q_bf (G2 out -> attn). After attn: orb_bf [4M,12M), wob_bf [12M,20M)
  //  [20M,36M) o_bf (attn out); x_bf [20M,28M) dead before attn writes.
  //  [36M,40M) wqa_bf  [40M,48M) wqb_bf  [48M,49M) wkv_bf
  //  [49M,53M) woa_bf  [53M,54M) kv_bf
  char* ws = (char*)d_ws;
  const size_t MB = 1024 * 1024;
  unsigned short* qa_bf   = (unsigned short*)(ws + 0 * MB);
  unsigned short* q_bf    = (unsigned short*)(ws + 4 * MB);
  unsigned short* orb_bf  = (unsigned short*)(ws + 4 * MB);
  unsigned short* wob_bf  = (unsigned short*)(ws + 12 * MB);
  unsigned short* o_bf    = (unsigned short*)(ws + 20 * MB);
  unsigned short* x_bf    = (unsigned short*)(ws + 20 * MB);
  unsigned short* wqa_bf  = (unsigned short*)(ws + 36 * MB);
  unsigned short* wqb_bf  = (unsigned short*)(ws + 40 * MB);
  unsigned short* wkv_bf  = (unsigned short*)(ws + 48 * MB);
  unsigned short* woa_bf  = (unsigned short*)(ws + 49 * MB);
  unsigned short* kv_bf   = (unsigned short*)(ws + 53 * MB);

  dim3 blk(256);

  // 0) fp32 -> bf16 conversions (wo_b deferred until after attention)
  f32_to_bf16<<<dim3(4096), blk, 0, stream>>>(x,      x_bf,   4 * 1024 * 1024 / 4);
  f32_to_bf16<<<dim3(2048), blk, 0, stream>>>(wq_a,   wqa_bf, 2 * 1024 * 1024 / 4);
  f32_to_bf16<<<dim3(4096), blk, 0, stream>>>(wq_b,   wqb_bf, 4 * 1024 * 1024 / 4);
  f32_to_bf16<<<dim3(512),  blk, 0, stream>>>(wkv,    wkv_bf, 512 * 1024 / 4);
  f32_to_bf16<<<dim3(2048), blk, 0, stream>>>(wo_a_w, woa_bf, 2 * 1024 * 1024 / 4);

  // 1) qa = x @ wq_a^T  (2048x1024, K=2048) -> bf16
  gemm_bf16<<<dim3(QL / 128, S_LEN / 128, 1), blk, 0, stream>>>(
      x_bf, wqa_bf, qa_bf, HID, HID, HID, QL, 0, 0, 0, 1);
  // 2) RMS in-place
  rmsnorm_bf_ip<<<dim3(S_LEN), blk, 0, stream>>>(qa_bf, q_norm_w, QL);
  // 3) q = qa @ wq_b^T  (2048x4096, K=1024) -> bf16
  gemm_bf16<<<dim3(NH * HD / 128, S_LEN / 128, 1), blk, 0, stream>>>(
      qa_bf, wqb_bf, q_bf, QL, QL, QL, NH * HD, 0, 0, 0, 1);
  // 4) per-(s,h) RMS + RoPE in-place
  qnorm_rope_ip<<<dim3(S_LEN * NH), blk, 0, stream>>>(q_bf, freqs);
  // 5) kv = x @ wkv^T   (2048x256, K=2048) -> bf16
  gemm_bf16<<<dim3(HD / 128, S_LEN / 128, 1), blk, 0, stream>>>(
      x_bf, wkv_bf, kv_bf, HID, HID, HID, HD, 0, 0, 0, 1);
  // 6) RMS + RoPE in-place
  kvnorm_rope_ip<<<dim3(S_LEN), blk, 0, stream>>>(kv_bf, kv_norm_w, freqs);
  // 7) flash attention -> o_bf
  attn_mfma<<<dim3(S_LEN / 64, NH), blk, 0, stream>>>(q_bf, kv_bf, sink, freqs, o_bf);
  // 7b) convert wo_b into [12M,20M) — q_bf dead after attention
  f32_to_bf16<<<dim3(4096), blk, 0, stream>>>(wo_b, wob_bf, 4 * 1024 * 1024 / 4);
  // 8) grouped projection via z-grid
  gemm_bf16<<<dim3(OR_ / 128, S_LEN / 128, NG), blk, 0, stream>>>(
      o_bf, woa_bf, orb_bf, HPG * HD, NH * HD, HPG * HD, NG * OR_,
      (long)(HPG * HD), (long)OR_ * (HPG * HD), (long)OR_, 1);
  // 9) out = orb @ wo_b^T (2048x2048, K=2048) -> fp32
  gemm_bf16<<<dim3(HID / 128, S_LEN / 128, 1), blk, 0, stream>>>(
      orb_bf, wob_bf, out, NG * OR_, NG * OR_, NG * OR_, HID, 0, 0, 0, 0);
}